// Round 18
// baseline (100.528 us; speedup 1.0000x reference)
//
#include <hip/hip_runtime.h>
#include <hip/hip_bf16.h>
#include <math.h>

#define BB 32
#define LL 2048
#define DD 1024
#define HH 16
#define DHH 64
#define NCK 16         // chunks per batch
#define CH  128        // rows per chunk
#define NT  8          // 16-row tiles per chunk

// ---- ws layout (float offsets) ----
#define WS_Q     1024       // 1024
#define WS_R     2048       // 16*1024
#define WS_C     18432      // 64 (16 used)
#define WS_CTX   19008      // 32768
#define WS_Y     51776      // 32768
#define WS_SSUM  84544      // 32*16*16 = 8192
#define WS_PART  92736      // 32*16*16*1024 bf16 = 16 MB

// ---- k_fused dynamic LDS layout (bytes) ----
// G tile buffers: 2 x (16 rows x 1024 e bf16, [4 l][16 e]-subtiled) = 2x32768
//   byte(l,e) = (e>>4)*512 + (l>>2)*128 + (l&3)*32 + (e&15)*2
//   buf regions are WAVE-PRIVATE (wave wv owns e16 in [wv*8, wv*8+8))
// red: 2 x (8 waves x 64 lanes x u16x4 bf16) = 2 x 4096  (double-buffered)
#define RED_OFF  65536
#define WT_OFF   73728      // 8 waves x 16 h x 16 l bf16 = 4096 (fallback only)
#define SMEM_BYTES 77824

typedef __attribute__((ext_vector_type(8))) short    bf16x8;
typedef __attribute__((ext_vector_type(4))) short    bf16x4;
typedef __attribute__((ext_vector_type(4))) float    f32x4;
typedef __attribute__((ext_vector_type(2))) unsigned u32x2;
typedef __attribute__((ext_vector_type(4))) unsigned short u16x4;
typedef __attribute__((ext_vector_type(8))) unsigned short u16x8;

#define MFMA(a, b, c) __builtin_amdgcn_mfma_f32_16x16x32_bf16(a, b, c, 0, 0, 0)

#if defined(__has_builtin)
#if __has_builtin(__builtin_amdgcn_mfma_f32_16x16x16bf16_1k)
#define HAVE_MFMA16 1
#define MFMA16(a, b, c) __builtin_amdgcn_mfma_f32_16x16x16bf16_1k(a, b, c, 0, 0, 0)
#endif
#endif
#ifndef HAVE_MFMA16
#define HAVE_MFMA16 0
#endif

__device__ __forceinline__ unsigned short f2bf(float f) {   // RNE f32->bf16
    unsigned u = __float_as_uint(f);
    return (unsigned short)((u + 0x7FFFu + ((u >> 16) & 1u)) >> 16);
}
// hot-path pack: v_cvt_pk_bf16_f32 via builtin (same RNE as f2bf)
__device__ __forceinline__ u16x4 pk4(float4 f) {
    __hip_bfloat162 a = __float22bfloat162_rn(make_float2(f.x, f.y));
    __hip_bfloat162 b = __float22bfloat162_rn(make_float2(f.z, f.w));
    ushort2 ua = *reinterpret_cast<ushort2*>(&a);
    ushort2 ub = *reinterpret_cast<ushort2*>(&b);
    u16x4 r; r[0] = ua.x; r[1] = ua.y; r[2] = ub.x; r[3] = ub.y;
    return r;
}
__device__ __forceinline__ u16x4 pk4v(f32x4 f) {
    return pk4(make_float4(f[0], f[1], f[2], f[3]));
}
__device__ __forceinline__ float bf2f(unsigned short u) {
    return __uint_as_float((unsigned)u << 16);
}
__device__ __forceinline__ float wave_sum(float v) {
#pragma unroll
    for (int s = 32; s >= 1; s >>= 1) v += __shfl_xor(v, s, 64);
    return v;
}

// ---------------- K1: q = Wq @ LN(sq[pos]) + bq  (LN fused, wave/output) ----
__global__ void k_q(const float* __restrict__ sq, const float* __restrict__ qn_w,
                    const float* __restrict__ qn_b, const int* __restrict__ pos,
                    const float* __restrict__ ipw, const float* __restrict__ ipb,
                    float* __restrict__ ws) {
    const int t = threadIdx.x;              // 256 threads
    const int w = t >> 6, lane = t & 63;
    __shared__ float q0s[DD];
    __shared__ float rs[4], rs2[4];
    {   // redundant per-block LN of the single query row (4 KB, L2-hot)
        const float4 x = ((const float4*)(sq + (size_t)pos[0] * DD))[t];
        float s  = x.x + x.y + x.z + x.w;
        float s2 = x.x * x.x + x.y * x.y + x.z * x.z + x.w * x.w;
        s = wave_sum(s); s2 = wave_sum(s2);
        if (lane == 0) { rs[w] = s; rs2[w] = s2; }
        __syncthreads();
        s  = rs[0] + rs[1] + rs[2] + rs[3];
        s2 = rs2[0] + rs2[1] + rs2[2] + rs2[3];
        const float mu  = s * (1.0f / DD);
        const float var = s2 * (1.0f / DD) - mu * mu;
        const float rstd = rsqrtf(var + 1e-5f);
        const float4 w4 = ((const float4*)qn_w)[t];
        const float4 b4 = ((const float4*)qn_b)[t];
        float4 o;
        o.x = (x.x - mu) * rstd * w4.x + b4.x;
        o.y = (x.y - mu) * rstd * w4.y + b4.y;
        o.z = (x.z - mu) * rstd * w4.z + b4.z;
        o.w = (x.w - mu) * rstd * w4.w + b4.w;
        ((float4*)q0s)[t] = o;
    }
    __syncthreads();
    const int d = blockIdx.x * 4 + w;       // 256 blocks * 4 waves = 1024 outputs
    const float* row = ipw + (size_t)d * DD;
    float acc = 0.f;
#pragma unroll
    for (int it = 0; it < 4; ++it) {
        float4 a = ((const float4*)row)[lane + 64 * it];
        float4 b = ((const float4*)q0s)[lane + 64 * it];
        acc += a.x * b.x + a.y * b.y + a.z * b.z + a.w * b.w;
    }
    acc = wave_sum(acc);
    if (lane == 0) (ws + WS_Q)[d] = acc + ipb[d];
}

// ------- K2: r_s[h,e] = scale * sum_j q[h,j] Wk[h*64+j, e]  (256 blocks) ----
__global__ void k_r(const float* __restrict__ ipw, const float* __restrict__ ipb,
                    float* __restrict__ ws) {
    const int h = blockIdx.x >> 4, s = blockIdx.x & 15;
    const int t = threadIdx.x;              // 64 threads
    const int e = s * 64 + t;
    const float* q = ws + WS_Q;
    const float* wk = ipw + (size_t)(DD + h * DHH) * DD;
    float acc = 0.f;
#pragma unroll 8
    for (int j = 0; j < DHH; ++j)
        acc += q[h * DHH + j] * wk[(size_t)j * DD + e];
    (ws + WS_R)[h * DD + e] = acc * 0.125f;
    if (s == 0) {
        float p = q[h * DHH + t] * ipb[DD + h * DHH + t];
        p = wave_sum(p);
        if (t == 0) (ws + WS_C)[h] = p * 0.125f;
    }
}

// ---------------- fused MFMA, wave-local staging, ONE barrier/tile ---------
// block = (b, 128-row chunk), 8 waves (512 thr); 8 tiles of 16 rows.
// Each wave stages ITS OWN e-strip (16 rows x 128 e) -> G buffers are
//   wave-private; stage->scores and PV->overwrite are own-wave lgkm-ordered.
//   Only the cross-wave score reduction `red` needs sync: double-buffered
//   (bf16), 1 barrier/tile.
// Per iter: finish(tt) [red[tt&1]] | stage(tt+1)+issue(tt+2) | PV(tt) |
//           scores(tt+1)->red[(tt+1)&1] | BARRIER.
// R18: PV A-fragment identity -- scores C/D layout gives lane (g,c16)
//   sa[reg]=score[row g*4+reg][h=c16], so after finish, ex[i] IS
//   A[m=c16][k=g*4+i] for the k=16 PV MFMA. The wt LDS write+read round-trip
//   was an identity permutation; deleted from the MFMA16 path (register-only
//   handoff, bit-identical values, shortens the per-tile serial chain).
__global__ __launch_bounds__(512, 4)
void k_fused(const float* __restrict__ gr, const float* __restrict__ ws,
             float* __restrict__ attn_e, unsigned short* __restrict__ part,
             float* __restrict__ ssum) {
    extern __shared__ char smem[];
    const int b  = blockIdx.x >> 4;
    const int ck = blockIdx.x & 15;
    const int l0 = ck * CH;
    const int t  = threadIdx.x;
    const int wv = t >> 6, lane = t & 63;
    const int c16 = lane & 15, g = lane >> 4;
    const int estrip = wv * 128;            // this wave's e-strip

    // ---- prologue: pack r into B-frags (4 k-steps x 32 e), bias ----
    bf16x8 rpk[4];
#pragma unroll
    for (int ks = 0; ks < 4; ++ks) {
        const float* rp = ws + WS_R + (size_t)c16 * DD + estrip + ks * 32 + g * 8;
        float4 f0 = *(const float4*)rp, f1 = *(const float4*)(rp + 4);
        u16x4 lo = pk4(f0), hi = pk4(f1);
        bf16x8 r;
        r[0] = (short)lo[0]; r[1] = (short)lo[1]; r[2] = (short)lo[2]; r[3] = (short)lo[3];
        r[4] = (short)hi[0]; r[5] = (short)hi[1]; r[6] = (short)hi[2]; r[7] = (short)hi[3];
        rpk[ks] = r;
    }
    const float myc = (ws + WS_C)[c16];

    f32x4 pv[8];
#pragma unroll
    for (int i = 0; i < 8; ++i) pv[i] = (f32x4){0.f, 0.f, 0.f, 0.f};
    float s_acc = 0.f;

    // ---- wave-local staging geometry ----
    const int srow = (lane >> 4) * 4 + ((lane >> 2) & 3);   // row 0..15
    const float* gbase = gr + ((size_t)(b * LL + l0) + srow) * DD +
                         estrip + (lane & 3) * 4;
    const int wr_base = (wv * 8) * 512 + (lane >> 4) * 128 +
                        ((lane >> 2) & 3) * 32 + (lane & 3) * 8;

    float4 raw[8];
    // tile 0: load + pack + write buf0 (own strip)
#pragma unroll
    for (int j = 0; j < 8; ++j) raw[j] = *(const float4*)(gbase + 16 * j);
#pragma unroll
    for (int j = 0; j < 8; ++j)
        *(u16x4*)(smem + wr_base + j * 512) = pk4(raw[j]);
    // issue tile 1 loads
#pragma unroll
    for (int j = 0; j < 8; ++j)
        raw[j] = *(const float4*)(gbase + 16 * DD + 16 * j);
    // scores(0) -> red[0]   (own-wave lgkm ordering covers stage->read)
    {
        f32x4 sa = {0.f, 0.f, 0.f, 0.f};
#pragma unroll
        for (int ks = 0; ks < 4; ++ks) {
            const int e16 = wv * 8 + ks * 2 + (g >> 1);
            const int byt = (e16 * 4 + (c16 >> 2)) * 128 + (c16 & 3) * 32 + (g & 1) * 16;
            bf16x8 a = *(const bf16x8*)(smem + byt);
            sa = MFMA(a, rpk[ks], sa);
        }
        *(u16x4*)(smem + RED_OFF + (wv * 64 + lane) * 8) = pk4v(sa);
    }
    __syncthreads();

#pragma unroll 1
    for (int tt = 0; tt < NT; ++tt) {
        // ---- finish(tt): sum 8 bf16 wave-partials + bias, exp ----
        f32x4 tot = {myc, myc, myc, myc};
#pragma unroll
        for (int w2 = 0; w2 < 8; ++w2) {
            u16x4 p = *(const u16x4*)(smem + RED_OFF + (tt & 1) * 4096 +
                                      (w2 * 64 + lane) * 8);
            tot[0] += bf2f(p[0]); tot[1] += bf2f(p[1]);
            tot[2] += bf2f(p[2]); tot[3] += bf2f(p[3]);
        }
        f32x4 ex;                           // no max-shift: |score| ~ O(1)
        ex[0] = __expf(tot[0]); ex[1] = __expf(tot[1]);
        ex[2] = __expf(tot[2]); ex[3] = __expf(tot[3]);
        const u16x4 exb = pk4v(ex);         // bf16 weights (register-resident)
#if !HAVE_MFMA16
        *(u16x4*)(smem + WT_OFF + wv * 512 + c16 * 32 + g * 8) = exb;
#endif
        if (wv == (tt & 7)) {               // attn store, rotated across waves
            float* ap = attn_e + ((size_t)b * HH + c16) * LL + l0 + tt * 16 + g * 4;
            *(float4*)ap = make_float4(ex[0], ex[1], ex[2], ex[3]);
        }
        s_acc += ex[0] + ex[1] + ex[2] + ex[3];
        // ---- stage tile tt+1 into buf[(tt+1)&1] (own strip), issue tt+2 ----
        if (tt < NT - 1) {
            char* wb = smem + ((tt + 1) & 1) * 32768;
#pragma unroll
            for (int j = 0; j < 8; ++j)
                *(u16x4*)(wb + wr_base + j * 512) = pk4(raw[j]);
            if (tt < NT - 2) {
                const float* gs = gbase + (size_t)(tt + 2) * 16 * DD;
#pragma unroll
                for (int j = 0; j < 8; ++j)
                    raw[j] = *(const float4*)(gs + 16 * j);
            }
        }
#if HAVE_MFMA16
        // ---- PV(tt) k=16 on buf[tt&1]: A = ex (register identity!) ----
        {
            bf16x4 afrag;
            afrag[0] = (short)exb[0]; afrag[1] = (short)exb[1];
            afrag[2] = (short)exb[2]; afrag[3] = (short)exb[3];
            u32x2 q[8];
#pragma unroll
            for (int nt = 0; nt < 8; ++nt) {
                const int est = wv * 8 + nt;
                const unsigned ta = (unsigned)((tt & 1) * 32768 + est * 512 +
                                               g * 128 + c16 * 8);
                asm volatile("ds_read_b64_tr_b16 %0, %1"
                             : "=v"(q[nt]) : "v"(ta));
            }
            asm volatile("s_waitcnt lgkmcnt(0)" ::: "memory");
            __builtin_amdgcn_sched_barrier(0);
#pragma unroll
            for (int nt = 0; nt < 8; ++nt) {
                union { unsigned u[2]; bf16x4 v; } bb;
                bb.u[0] = q[nt][0]; bb.u[1] = q[nt][1];
                pv[nt] = MFMA16(afrag, bb.v, pv[nt]);
            }
        }
#else
        // ---- PV(tt) fallback: k=32 with zero-padded A (wt LDS path) ----
        {
            bf16x8 afrag;
            if (g < 2) {
                afrag = *(const bf16x8*)(smem + WT_OFF + wv * 512 + c16 * 32 + g * 16);
            } else {
                afrag = (bf16x8){0, 0, 0, 0, 0, 0, 0, 0};
            }
#pragma unroll
            for (int grp = 0; grp < 2; ++grp) {
                u32x2 q[8];
#pragma unroll
                for (int n2 = 0; n2 < 4; ++n2) {
                    const int est = wv * 8 + grp * 4 + n2;
                    const unsigned ta = (unsigned)((tt & 1) * 32768 + est * 512 +
                                                   (g & 1) * 256 + c16 * 8);
                    asm volatile("ds_read_b64_tr_b16 %0, %1"
                                 : "=v"(q[n2 * 2]) : "v"(ta));
                    asm volatile("ds_read_b64_tr_b16 %0, %1 offset:128"
                                 : "=v"(q[n2 * 2 + 1]) : "v"(ta));
                }
                asm volatile("s_waitcnt lgkmcnt(0)" ::: "memory");
                __builtin_amdgcn_sched_barrier(0);
#pragma unroll
                for (int n2 = 0; n2 < 4; ++n2) {
                    union { unsigned u[4]; bf16x8 v; } bb;
                    bb.u[0] = q[n2 * 2][0];     bb.u[1] = q[n2 * 2][1];
                    bb.u[2] = q[n2 * 2 + 1][0]; bb.u[3] = q[n2 * 2 + 1][1];
                    pv[grp * 4 + n2] = MFMA(afrag, bb.v, pv[grp * 4 + n2]);
                }
            }
        }
#endif
        // ---- scores(tt+1) on buf[(tt+1)&1] -> red[(tt+1)&1] ----
        if (tt < NT - 1) {
            const char* rb = smem + ((tt + 1) & 1) * 32768;
            f32x4 sa = {0.f, 0.f, 0.f, 0.f};
#pragma unroll
            for (int ks = 0; ks < 4; ++ks) {
                const int e16 = wv * 8 + ks * 2 + (g >> 1);
                const int byt = (e16 * 4 + (c16 >> 2)) * 128 + (c16 & 3) * 32 + (g & 1) * 16;
                bf16x8 a = *(const bf16x8*)(rb + byt);
                sa = MFMA(a, rpk[ks], sa);
            }
            *(u16x4*)(smem + RED_OFF + ((tt + 1) & 1) * 4096 +
                      (wv * 64 + lane) * 8) = pk4v(sa);
        }
        __syncthreads();                    // red[(tt+1)&1] visible; red[tt&1] free
    }
    // ---- epilogue: ssum + COALESCED partials via LDS transpose ----
    float sv = s_acc;                       // identical in all waves
    sv += __shfl_xor(sv, 16, 64);
    sv += __shfl_xor(sv, 32, 64);
    if (wv == 0 && lane < 16)
        ssum[((size_t)b * NCK + ck) * HH + c16] = sv;
    // All waves passed the loop's final barrier -> G buffers dead. Transpose
    // pv into smem[0..32KB) as [16 h][1024 e] bf16.
    {
        unsigned short* tb = (unsigned short*)smem;
#pragma unroll
        for (int nt = 0; nt < 8; ++nt)
#pragma unroll
            for (int r2 = 0; r2 < 4; ++r2)
                tb[(g * 4 + r2) * DD + estrip + nt * 16 + c16] = f2bf(pv[nt][r2]);
    }
    __syncthreads();
    {   // thread t stores a contiguous 64B run: 4 x global_store_dwordx4
        const unsigned short* tb = (const unsigned short*)smem;
        unsigned short* pp = part + ((size_t)b * NCK + ck) * (HH * DD) + t * 32;
#pragma unroll
        for (int i = 0; i < 4; ++i)
            *(u16x8*)(pp + i * 8) = *(const u16x8*)(tb + t * 32 + i * 8);
    }
}

// ---------------- combine + attn-normalize + Wv: ctx[b, h*64+j] ------------
__global__ void k_ctx(const float* __restrict__ ipw, const float* __restrict__ ipb,
                      const unsigned short* __restrict__ part,
                      const float* __restrict__ ssum,
                      float* __restrict__ attn_e, float* __restrict__ ctx) {
    const int bh = blockIdx.x, b = bh >> 4, h = bh & 15;   // 512 blocks
    const int t = threadIdx.x, w = t >> 6, lane = t & 63;  // 256
    float S = 0.f;
#pragma unroll
    for (int c = 0; c < NCK; ++c) S += ssum[((size_t)b * NCK + c) * HH + h];
    const float inv = 1.0f / S;
    float4* ar = (float4*)(attn_e + (size_t)bh * LL);
#pragma unroll
    for (int i = 0; i < 2; ++i) {
        float4 v = ar[t + 256 * i];
        v.x *= inv; v.y *= inv; v.z *= inv; v.w *= inv;
        ar[t + 256 * i] = v;
    }
    __shared__ float Xl[DD];
    float4 x = {0.f, 0.f, 0.f, 0.f};
#pragma unroll
    for (int c = 0; c < NCK; ++c) {
        u16x4 p = *(const u16x4*)(part + ((size_t)b * NCK + c) * (HH * DD) +
                                  (size_t)h * DD + t * 4);
        x.x += bf2f(p[0]); x.y += bf2f(p[1]);
        x.z += bf2f(p[2]); x.w += bf2f(p[3]);
    }
    float4 xs = {x.x * inv, x.y * inv, x.z * inv, x.w * inv};
    ((float4*)Xl)[t] = xs;
    __syncthreads();
    for (int jj = 0; jj < 16; ++jj) {
        const int j = w * 16 + jj;
        const float* row = ipw + (size_t)(2 * DD + h * DHH + j) * DD;
        float acc = 0.f;
#pragma unroll
        for (int it = 0; it < 4; ++it) {
            float4 a = ((const float4*)row)[lane + 64 * it];
            float4 p = ((const float4*)Xl)[lane + 64 * it];
            acc += a.x * p.x + a.y * p.y + a.z * p.z + a.w * p.w;
        }
        acc = wave_sum(acc);
        if (lane == 0) ctx[(size_t)b * DD + h * DHH + j] = acc + ipb[2 * DD + h * DHH + j];
    }
}

// ---------------- y[b, d'] = out_w[d',:]·ctx[b,:] + out_b ----------------
__global__ void k_y(const float* __restrict__ ow, const float* __restrict__ ob,
                    const float* __restrict__ ctx, float* __restrict__ y) {
    const int blk = blockIdx.x, b = blk >> 4, ch = blk & 15;  // 512 blocks
    const int t = threadIdx.x, w = t >> 6, lane = t & 63;     // 256
    __shared__ float Xl[DD];
    ((float4*)Xl)[t] = ((const float4*)(ctx + (size_t)b * DD))[t];
    __syncthreads();
    for (int jj = 0; jj < 16; ++jj) {
        const int d = ch * 64 + w * 16 + jj;
        const float* row = ow + (size_t)d * DD;
        float acc = 0.f;
#pragma unroll
        for (int it = 0; it < 4; ++it) {
            float4 a = ((const float4*)row)[lane + 64 * it];
            float4 p = ((const float4*)Xl)[lane + 64 * it];
            acc += a.x * p.x + a.y * p.y + a.z * p.z + a.w * p.w;
        }
        acc = wave_sum(acc);
        if (lane == 0) y[(size_t)b * DD + d] = acc + ob[d];
    }
}

// ---------------- final LN -> pooled output ----------------
__global__ void k_lnout(const float* __restrict__ y, const float* __restrict__ on_w,
                        const float* __restrict__ on_b, float* __restrict__ outp) {
    const int b = blockIdx.x, t = threadIdx.x;   // 32 blocks, 256 threads
    const float4 x = ((const float4*)(y + (size_t)b * DD))[t];
    float s  = x.x + x.y + x.z + x.w;
    float s2 = x.x * x.x + x.y * x.y + x.z * x.z + x.w * x.w;
    __shared__ float rs[4], rs2[4];
    s = wave_sum(s); s2 = wave_sum(s2);
    const int w = t >> 6, lane = t & 63;
    if (lane == 0) { rs[w] = s; rs2[w] = s2; }
    __syncthreads();
    s  = rs[0] + rs[1] + rs[2] + rs[3];
    s2 = rs2[0] + rs2[1] + rs2[2] + rs2[3];
    const float mu  = s * (1.0f / DD);
    const float var = s2 * (1.0f / DD) - mu * mu;
    const float rstd = rsqrtf(var + 1e-5f);
    const float4 w4 = ((const float4*)on_w)[t];
    const float4 b4 = ((const float4*)on_b)[t];
    float4 o;
    o.x = (x.x - mu) * rstd * w4.x + b4.x;
    o.y = (x.y - mu) * rstd * w4.y + b4.y;
    o.z = (x.z - mu) * rstd * w4.z + b4.z;
    o.w = (x.w - mu) * rstd * w4.w + b4.w;
    ((float4*)(outp + (size_t)b * DD))[t] = o;
}

extern "C" void kernel_launch(void* const* d_in, const int* in_sizes, int n_in,
                              void* d_out, int out_size, void* d_ws, size_t ws_size,
                              hipStream_t stream) {
    const float* gr   = (const float*)d_in[0];
    const float* sq   = (const float*)d_in[1];
    const float* qn_w = (const float*)d_in[2];
    const float* qn_b = (const float*)d_in[3];
    const float* ipw  = (const float*)d_in[4];
    const float* ipb  = (const float*)d_in[5];
    const float* ow   = (const float*)d_in[6];
    const float* ob   = (const float*)d_in[7];
    const float* on_w = (const float*)d_in[8];
    const float* on_b = (const float*)d_in[9];
    const int*   pos  = (const int*)d_in[10];

    float* out  = (float*)d_out;
    float* attn = out + BB * DD;           // output 1; holds exp(score) until k_ctx norms
    float* ws   = (float*)d_ws;
    unsigned short* part16 = (unsigned short*)(ws + WS_PART);

    hipFuncSetAttribute((const void*)k_fused,
                        hipFuncAttributeMaxDynamicSharedMemorySize, SMEM_BYTES);

    k_q<<<256, 256, 0, stream>>>(sq, qn_w, qn_b, pos, ipw, ipb, ws);
    k_r<<<256, 64, 0, stream>>>(ipw, ipb, ws);
    k_fused<<<BB * NCK, 512, SMEM_BYTES, stream>>>(gr, ws, attn,
                                                   part16, ws + WS_SSUM);
    k_ctx<<<BB * HH, 256, 0, stream>>>(ipw, ipb, part16, ws + WS_SSUM,
                                       attn, ws + WS_CTX);
    k_y<<<BB * 16, 256, 0, stream>>>(ow, ob, ws + WS_CTX, ws + WS_Y);
    k_lnout<<<BB, 256, 0, stream>>>(ws + WS_Y, on_w, on_b, out);
}